// Round 3
// 335.231 us; speedup vs baseline: 1.0164x; 1.0164x over previous
//
#include <hip/hip_runtime.h>
#include <math.h>

#define EPSF 1e-8f
// f32 nearest to 2*pi
#define TWO_PI_F 6.28318530717958647692f

// Native clang vector type — required by __builtin_nontemporal_store
// (HIP's float4 class type is rejected by the builtin).
typedef float f32x4 __attribute__((ext_vector_type(4)));

// ---------------------------------------------------------------------------
// EXACT path (verbatim from the verified 340us kernel, absmax 0.0039).
// Only used for pixels in the hue-wrap neighborhood (h ~ 1.0), where the
// reference's atan2-roundtrip can round h' to exactly 1.0f -> hi==6 -> the
// jnp.select default ZERO output. That discontinuity must be replicated
// bit-faithfully; everywhere else the roundtrip is algebraically the identity.
// ---------------------------------------------------------------------------
__device__ __forceinline__ void hvi_exact(float r, float g, float b, float k,
                                          float& ro, float& go, float& bo)
{
    float value = fmaxf(r, fmaxf(g, b));
    float vmin  = fminf(r, fminf(g, b));
    float diff  = value - vmin + EPSF;

    bool isR = (r == value);
    bool isG = (!isR) && (g == value);

    float num  = isR ? (g - b) : (isG ? (b - r) : (r - g));
    float offs = isR ? 0.0f   : (isG ? 2.0f    : 4.0f);
    float x    = num / diff;                 // IEEE divide (matches np)
    float hue6 = offs + x;
    if (isR && x < 0.0f) hue6 = x + 6.0f;    // np mod semantics
    if (vmin == value)   hue6 = 0.0f;
    float hue = hue6 / 6.0f;                 // 6.0/6.0 == 1.0 exactly

    float sat = (value == 0.0f) ? 0.0f : (value - vmin) / (value + EPSF);

    float sv = __sinf((value * 0.5f) * 3.14159265358979323846f) + EPSF;
    float cs = __expf(k * __logf(sv));

    float ang = TWO_PI_F * hue;
    float sh, ch;
    sincosf(ang, &sh, &ch);                  // precise libm

    float X = cs * sat * ch;
    float Y = cs * sat * sh;

    // ---- _phvit ----
    float H = fminf(fmaxf(X, -1.0f), 1.0f);
    float V = fminf(fmaxf(Y, -1.0f), 1.0f);
    float v = fminf(fmaxf(value, 0.0f), 1.0f);

    float csd = cs + EPSF;
    H = fminf(fmaxf(H / csd, -1.0f), 1.0f);
    V = fminf(fmaxf(V / csd, -1.0f), 1.0f);

    float t2 = atan2f(V, H) / TWO_PI_F;      // precise atan2 + IEEE divide
    float h  = (t2 < 0.0f) ? t2 + 1.0f : t2; // np mod(x, 1.0) -> can hit 1.0f
    float s  = fminf(fmaxf(sqrtf(H * H + V * V), 0.0f), 1.0f);

    float h6  = h * 6.0f;
    float hif = floorf(h6);
    float f   = h6 - hif;
    float pv  = v * (1.0f - s);
    float qv  = v * (1.0f - f * s);
    float tv  = v * (1.0f - (1.0f - f) * s);
    int hi = (int)hif;

    float rr = 0.0f, gg = 0.0f, bb = 0.0f;   // hi==6 falls through to zero
    rr = (hi == 0) ? v  : rr;  gg = (hi == 0) ? tv : gg;  bb = (hi == 0) ? pv : bb;
    rr = (hi == 1) ? qv : rr;  gg = (hi == 1) ? v  : gg;  bb = (hi == 1) ? pv : bb;
    rr = (hi == 2) ? pv : rr;  gg = (hi == 2) ? v  : gg;  bb = (hi == 2) ? tv : bb;
    rr = (hi == 3) ? pv : rr;  gg = (hi == 3) ? qv : gg;  bb = (hi == 3) ? v  : bb;
    rr = (hi == 4) ? tv : rr;  gg = (hi == 4) ? pv : gg;  bb = (hi == 4) ? v  : bb;
    rr = (hi == 5) ? v  : rr;  gg = (hi == 5) ? pv : gg;  bb = (hi == 5) ? qv : bb;

    ro = rr; go = gg; bo = bb;
}

// ---------------------------------------------------------------------------
// FAST path: _phvit(_hvit(rgb)) is algebraically the identity roundtrip:
//   h' = atan2(b*sin, b*cos)/2pi mod 1 == h        (b = sat*cs/(cs+eps) > 0)
//   s' = b = sat * cs/(cs+eps) = sat * (1 - eps/(cs+eps)),  eps/(cs+eps) <= 4e-7
// so output = hsv_reconstruct(h, sat, v). The cs factor, sincos, atan2, sqrt
// and the H/V divides all cancel; dropping them perturbs the result by <~1e-5
// vs the fp32 reference (its own trig rounding noise is the same order),
// far below the current 3.9e-3 absmax. Fast v_rcp_f32 (rel err < 2.4e-7)
// replaces IEEE divides; all hi-bucket boundaries are continuous, so the
// ~1e-6 h jitter only produces ~1e-6 output jitter.
// ---------------------------------------------------------------------------
__device__ __forceinline__ void hvi_pixel(float r, float g, float b, float k,
                                          float& ro, float& go, float& bo)
{
    float value = fmaxf(r, fmaxf(g, b));
    float vmin  = fminf(r, fminf(g, b));
    float sv    = value - vmin;
    float diff  = sv + EPSF;

    bool isR = (r == value);
    bool isG = (!isR) && (g == value);

    float num  = isR ? (g - b) : (isG ? (b - r) : (r - g));
    float offs = isR ? 0.0f   : (isG ? 2.0f    : 4.0f);
    float x    = num * __builtin_amdgcn_rcpf(diff);
    float h6   = offs + x;
    if (isR && x < 0.0f) h6 = x + 6.0f;      // np mod semantics (wrap)
    if (vmin == value)   h6 = 0.0f;

    // Hue-wrap neighborhood: reference may round h' to exactly 1.0 -> zero
    // output. Window is ~3000x wider than the dangerous band (~6e-8 in h),
    // triggers on ~1.7e-4 of pixels -> negligible divergence cost.
    if (__builtin_expect(h6 > 5.9995f, 0)) {
        hvi_exact(r, g, b, k, ro, go, bo);
        return;
    }

    float sat = sv * __builtin_amdgcn_rcpf(value + EPSF);  // ==0 for grey/black

    float hif = floorf(h6);
    float f   = h6 - hif;
    int   hi  = (int)hif;                    // in [0,5] here, never 6

    float v  = value;
    float vs = v * sat;
    float pv = v - vs;                       // v*(1-s)
    float qv = v - vs * f;                   // v*(1-f*s)
    float tv = v - vs * (1.0f - f);          // v*(1-(1-f)*s)

    float rr = (hi == 0) ? v  : (hi == 1) ? qv : (hi == 2) ? pv
             : (hi == 3) ? pv : (hi == 4) ? tv : v;
    float gg = (hi == 0) ? tv : (hi == 1) ? v  : (hi == 2) ? v
             : (hi == 3) ? qv : (hi == 4) ? pv : pv;
    float bb = (hi == 0) ? pv : (hi == 1) ? pv : (hi == 2) ? tv
             : (hi == 3) ? v  : (hi == 4) ? v  : qv;

    ro = rr; go = gg; bo = bb;
}

// Layout: (N=16, C=3, H*W = 1<<20). Channel stride = 1M floats, image stride
// = 3M floats. One thread handles 4 consecutive pixels -> float4 per plane,
// fully coalesced. Output is write-once -> nontemporal stores (less L2/L3
// pollution, keeps more of the input resident).
extern "C" __global__ void __launch_bounds__(256)
rgb_hvi_kernel(const float* __restrict__ img, const float* __restrict__ kptr,
               float* __restrict__ out, int ngroups)
{
    int i = blockIdx.x * blockDim.x + threadIdx.x;
    if (i >= ngroups) return;
    const float k = kptr[0];

    unsigned int q = (unsigned int)i << 2;        // pixel index
    unsigned int n = q >> 20;                     // image index
    unsigned int p = q & 1048575u;                // pixel within image
    size_t base = (size_t)n * 3145728u + p;

    const float4 R = *reinterpret_cast<const float4*>(img + base);
    const float4 G = *reinterpret_cast<const float4*>(img + base + 1048576);
    const float4 B = *reinterpret_cast<const float4*>(img + base + 2097152);

    // Scalar locals (can't bind float& to ext_vector elements).
    float r0,g0,b0, r1,g1,b1, r2,g2,b2, r3,g3,b3;
    hvi_pixel(R.x, G.x, B.x, k, r0, g0, b0);
    hvi_pixel(R.y, G.y, B.y, k, r1, g1, b1);
    hvi_pixel(R.z, G.z, B.z, k, r2, g2, b2);
    hvi_pixel(R.w, G.w, B.w, k, r3, g3, b3);

    f32x4 Ro = { r0, r1, r2, r3 };
    f32x4 Go = { g0, g1, g2, g3 };
    f32x4 Bo = { b0, b1, b2, b3 };

    __builtin_nontemporal_store(Ro, reinterpret_cast<f32x4*>(out + base));
    __builtin_nontemporal_store(Go, reinterpret_cast<f32x4*>(out + base + 1048576));
    __builtin_nontemporal_store(Bo, reinterpret_cast<f32x4*>(out + base + 2097152));
}

extern "C" void kernel_launch(void* const* d_in, const int* in_sizes, int n_in,
                              void* d_out, int out_size, void* d_ws, size_t ws_size,
                              hipStream_t stream)
{
    const float* img  = (const float*)d_in[0];
    const float* kptr = (const float*)d_in[1];
    float* out = (float*)d_out;

    int total   = in_sizes[0];        // 16*3*1024*1024 = 50331648
    int ngroups = total / 12;         // pixels/4 = 4194304
    int block   = 256;
    int grid    = (ngroups + block - 1) / block;

    rgb_hvi_kernel<<<grid, block, 0, stream>>>(img, kptr, out, ngroups);
}

// Round 4
// 327.080 us; speedup vs baseline: 1.0418x; 1.0249x over previous
//
#include <hip/hip_runtime.h>
#include <math.h>

#define EPSF 1e-8f
// f32 nearest to 2*pi
#define TWO_PI_F 6.28318530717958647692f

// ---------------------------------------------------------------------------
// EXACT path (verbatim from the verified 340us kernel, absmax 0.0039).
// Only used for pixels in the hue-wrap neighborhood (h ~ 1.0), where the
// reference's atan2-roundtrip can round h' to exactly 1.0f -> hi==6 -> the
// jnp.select default ZERO output. That discontinuity must be replicated
// bit-faithfully; everywhere else the roundtrip is algebraically the identity.
// ---------------------------------------------------------------------------
__device__ __forceinline__ void hvi_exact(float r, float g, float b, float k,
                                          float& ro, float& go, float& bo)
{
    float value = fmaxf(r, fmaxf(g, b));
    float vmin  = fminf(r, fminf(g, b));
    float diff  = value - vmin + EPSF;

    bool isR = (r == value);
    bool isG = (!isR) && (g == value);

    float num  = isR ? (g - b) : (isG ? (b - r) : (r - g));
    float offs = isR ? 0.0f   : (isG ? 2.0f    : 4.0f);
    float x    = num / diff;                 // IEEE divide (matches np)
    float hue6 = offs + x;
    if (isR && x < 0.0f) hue6 = x + 6.0f;    // np mod semantics
    if (vmin == value)   hue6 = 0.0f;
    float hue = hue6 / 6.0f;                 // 6.0/6.0 == 1.0 exactly

    float sat = (value == 0.0f) ? 0.0f : (value - vmin) / (value + EPSF);

    float sv = __sinf((value * 0.5f) * 3.14159265358979323846f) + EPSF;
    float cs = __expf(k * __logf(sv));

    float ang = TWO_PI_F * hue;
    float sh, ch;
    sincosf(ang, &sh, &ch);                  // precise libm

    float X = cs * sat * ch;
    float Y = cs * sat * sh;

    // ---- _phvit ----
    float H = fminf(fmaxf(X, -1.0f), 1.0f);
    float V = fminf(fmaxf(Y, -1.0f), 1.0f);
    float v = fminf(fmaxf(value, 0.0f), 1.0f);

    float csd = cs + EPSF;
    H = fminf(fmaxf(H / csd, -1.0f), 1.0f);
    V = fminf(fmaxf(V / csd, -1.0f), 1.0f);

    float t2 = atan2f(V, H) / TWO_PI_F;      // precise atan2 + IEEE divide
    float h  = (t2 < 0.0f) ? t2 + 1.0f : t2; // np mod(x, 1.0) -> can hit 1.0f
    float s  = fminf(fmaxf(sqrtf(H * H + V * V), 0.0f), 1.0f);

    float h6  = h * 6.0f;
    float hif = floorf(h6);
    float f   = h6 - hif;
    float pv  = v * (1.0f - s);
    float qv  = v * (1.0f - f * s);
    float tv  = v * (1.0f - (1.0f - f) * s);
    int hi = (int)hif;

    float rr = 0.0f, gg = 0.0f, bb = 0.0f;   // hi==6 falls through to zero
    rr = (hi == 0) ? v  : rr;  gg = (hi == 0) ? tv : gg;  bb = (hi == 0) ? pv : bb;
    rr = (hi == 1) ? qv : rr;  gg = (hi == 1) ? v  : gg;  bb = (hi == 1) ? pv : bb;
    rr = (hi == 2) ? pv : rr;  gg = (hi == 2) ? v  : gg;  bb = (hi == 2) ? tv : bb;
    rr = (hi == 3) ? pv : rr;  gg = (hi == 3) ? qv : gg;  bb = (hi == 3) ? v  : bb;
    rr = (hi == 4) ? tv : rr;  gg = (hi == 4) ? pv : gg;  bb = (hi == 4) ? v  : bb;
    rr = (hi == 5) ? v  : rr;  gg = (hi == 5) ? pv : gg;  bb = (hi == 5) ? qv : bb;

    ro = rr; go = gg; bo = bb;
}

// ---------------------------------------------------------------------------
// FAST path: _phvit(_hvit(rgb)) is algebraically the identity roundtrip:
//   h' = atan2(b*sin, b*cos)/2pi mod 1 == h        (b = sat*cs/(cs+eps) > 0)
//   s' = b = sat * cs/(cs+eps) = sat * (1 - eps/(cs+eps)),  eps/(cs+eps) <= 4e-7
// so output = hsv_reconstruct(h, sat, v). The cs factor, sincos, atan2, sqrt
// and the H/V divides all cancel; dropping them perturbs the result by <~1e-5
// vs the fp32 reference, far below the verified 3.9e-3 absmax. Fast v_rcp_f32
// (rel err < 2.4e-7) replaces IEEE divides; all hi-bucket boundaries are
// continuous, so ~1e-6 h jitter only produces ~1e-6 output jitter.
// ---------------------------------------------------------------------------
__device__ __forceinline__ void hvi_pixel(float r, float g, float b, float k,
                                          float& ro, float& go, float& bo)
{
    float value = fmaxf(r, fmaxf(g, b));
    float vmin  = fminf(r, fminf(g, b));
    float sv    = value - vmin;
    float diff  = sv + EPSF;

    bool isR = (r == value);
    bool isG = (!isR) && (g == value);

    float num  = isR ? (g - b) : (isG ? (b - r) : (r - g));
    float offs = isR ? 0.0f   : (isG ? 2.0f    : 4.0f);
    float x    = num * __builtin_amdgcn_rcpf(diff);
    float h6   = offs + x;
    if (isR && x < 0.0f) h6 = x + 6.0f;      // np mod semantics (wrap)
    if (vmin == value)   h6 = 0.0f;

    // Hue-wrap neighborhood: reference may round h' to exactly 1.0 -> zero
    // output. Window is ~2800x wider than the dangerous band, triggers on
    // ~8e-5 of pixels -> negligible divergence cost.
    if (__builtin_expect(h6 > 5.9995f, 0)) {
        hvi_exact(r, g, b, k, ro, go, bo);
        return;
    }

    float sat = sv * __builtin_amdgcn_rcpf(value + EPSF);  // ==0 for grey/black

    float hif = floorf(h6);
    float f   = h6 - hif;
    int   hi  = (int)hif;                    // in [0,5] here, never 6

    float v  = value;
    float vs = v * sat;
    float pv = v - vs;                       // v*(1-s)
    float qv = v - vs * f;                   // v*(1-f*s)
    float tv = v - vs * (1.0f - f);          // v*(1-(1-f)*s)

    float rr = (hi == 0) ? v  : (hi == 1) ? qv : (hi == 2) ? pv
             : (hi == 3) ? pv : (hi == 4) ? tv : v;
    float gg = (hi == 0) ? tv : (hi == 1) ? v  : (hi == 2) ? v
             : (hi == 3) ? qv : (hi == 4) ? pv : pv;
    float bb = (hi == 0) ? pv : (hi == 1) ? pv : (hi == 2) ? tv
             : (hi == 3) ? v  : (hi == 4) ? v  : qv;

    ro = rr; go = gg; bo = bb;
}

// Layout: (N=16, C=3, H*W = 1<<20). Channel stride = 1M floats, image stride
// = 3M floats. One thread handles 4 consecutive pixels -> float4 per plane,
// fully coalesced. A/B vs round 3: PLAIN stores (nontemporal reverted —
// suspected NT no-allocate path loses L2 write-combining on gfx950 and
// halves effective store BW).
extern "C" __global__ void __launch_bounds__(256)
rgb_hvi_kernel(const float* __restrict__ img, const float* __restrict__ kptr,
               float* __restrict__ out, int ngroups)
{
    int i = blockIdx.x * blockDim.x + threadIdx.x;
    if (i >= ngroups) return;
    const float k = kptr[0];

    unsigned int q = (unsigned int)i << 2;        // pixel index
    unsigned int n = q >> 20;                     // image index
    unsigned int p = q & 1048575u;                // pixel within image
    size_t base = (size_t)n * 3145728u + p;

    const float4 R = *reinterpret_cast<const float4*>(img + base);
    const float4 G = *reinterpret_cast<const float4*>(img + base + 1048576);
    const float4 B = *reinterpret_cast<const float4*>(img + base + 2097152);

    float r0,g0,b0, r1,g1,b1, r2,g2,b2, r3,g3,b3;
    hvi_pixel(R.x, G.x, B.x, k, r0, g0, b0);
    hvi_pixel(R.y, G.y, B.y, k, r1, g1, b1);
    hvi_pixel(R.z, G.z, B.z, k, r2, g2, b2);
    hvi_pixel(R.w, G.w, B.w, k, r3, g3, b3);

    float4 Ro = make_float4(r0, r1, r2, r3);
    float4 Go = make_float4(g0, g1, g2, g3);
    float4 Bo = make_float4(b0, b1, b2, b3);

    *reinterpret_cast<float4*>(out + base)           = Ro;
    *reinterpret_cast<float4*>(out + base + 1048576) = Go;
    *reinterpret_cast<float4*>(out + base + 2097152) = Bo;
}

extern "C" void kernel_launch(void* const* d_in, const int* in_sizes, int n_in,
                              void* d_out, int out_size, void* d_ws, size_t ws_size,
                              hipStream_t stream)
{
    const float* img  = (const float*)d_in[0];
    const float* kptr = (const float*)d_in[1];
    float* out = (float*)d_out;

    int total   = in_sizes[0];        // 16*3*1024*1024 = 50331648
    int ngroups = total / 12;         // pixels/4 = 4194304
    int block   = 256;
    int grid    = (ngroups + block - 1) / block;

    rgb_hvi_kernel<<<grid, block, 0, stream>>>(img, kptr, out, ngroups);
}